// Round 7
// baseline (325.690 us; speedup 1.0000x reference)
//
#include <hip/hip_runtime.h>

#define N_NODES 50000
#define N_EDGES 800000
#define N_GRAPHS 512
#define D 64

// XOR swizzle for the LDS X tile: element (k,n) lives at word k*64 + SWZ(k,n).
// Keeps b128 row reads conflict-free; gather's column writes drop from 32-way
// to 8-way (only 16 scalar writes per thread, negligible).
#define SWZ(k, n) ((n) ^ (((k) & 7) << 2))

// ---------------- prep: zero deg + graph start offsets ----------------
__global__ __launch_bounds__(256) void prep_kernel(
    const int* __restrict__ batch, int* __restrict__ deg, int* __restrict__ start)
{
    int i = blockIdx.x * 256 + threadIdx.x;
    if (i < N_NODES / 4)
        ((int4*)deg)[i] = make_int4(0, 0, 0, 0);
    if (i < N_NODES) {
        int g = batch[i];
        int gp = (i == 0) ? -1 : batch[i - 1];
        for (int gg = gp + 1; gg <= g; ++gg) start[gg] = i;
        if (i == N_NODES - 1)
            for (int gg = g + 1; gg <= N_GRAPHS; ++gg) start[gg] = N_NODES;
    }
}

// ---------------- CSR build (by dst), ONE atomic pass ----------------
__global__ __launch_bounds__(256) void hist_rank_kernel(
    const int* __restrict__ dst, int* __restrict__ deg, int* __restrict__ rank)
{
    int e = blockIdx.x * blockDim.x + threadIdx.x;
    if (e < N_EDGES) rank[e] = atomicAdd(&deg[dst[e]], 1);
}

// Single-block scan of deg -> exclusive rowptr. 1024 threads x 49 elements.
#define SCAN_T 1024
#define SCAN_C 49
__global__ __launch_bounds__(SCAN_T) void scan_all_kernel(
    const int* __restrict__ deg, int* __restrict__ rowptr)
{
    __shared__ int part[SCAN_T];
    int t = threadIdx.x;
    int base = t * SCAN_C;
    int s = 0;
    for (int i = 0; i < SCAN_C; ++i) {
        int idx = base + i;
        s += (idx < N_NODES) ? deg[idx] : 0;
    }
    part[t] = s;
    __syncthreads();
    for (int off = 1; off < SCAN_T; off <<= 1) {
        int x = (t >= off) ? part[t - off] : 0;
        __syncthreads();
        part[t] += x;
        __syncthreads();
    }
    int run = part[t] - s;   // exclusive prefix of this chunk
    for (int i = 0; i < SCAN_C; ++i) {
        int idx = base + i;
        if (idx < N_NODES) {
            int v = deg[idx];
            rowptr[idx] = run;
            run += v;
        }
    }
    if (t == 0) rowptr[N_NODES] = N_EDGES;
}

// Non-atomic fill: position fully determined by rowptr + rank.
__global__ __launch_bounds__(256) void fill_scatter_kernel(
    const int* __restrict__ src, const int* __restrict__ dst,
    const int* __restrict__ rank, const int* __restrict__ rowptr,
    int* __restrict__ eidx)
{
    int e = blockIdx.x * blockDim.x + threadIdx.x;
    if (e < N_EDGES) eidx[rowptr[dst[e]] + rank[e]] = src[e];
}

// ---------------- fused gather + GIN MLP ----------------
// Block = 256 threads = 4 waves, 64 nodes. Gather: each wave owns 16 nodes,
// lane = feature dim -> coalesced 256B row loads; acc written to swizzled
// LDS X tile. MLP: 4x4 register tile, b128 LDS reads, Wb staged via regs.
__global__ __launch_bounds__(256) void gin_fused_kernel(
    const float* __restrict__ x,
    const int* __restrict__ rowptr, const int* __restrict__ eidx,
    const float* __restrict__ wa, const float* __restrict__ ba,
    const float* __restrict__ wb, const float* __restrict__ bb,
    float* __restrict__ xout)
{
    __shared__ float sX[D * D];   // swizzled [k][n], then [hk][n]
    __shared__ float sW[D * D];   // natural [k][od]: Wa, then Wb
    const int t = threadIdx.x;
    const int lane = t & 63;
    const int wv = __builtin_amdgcn_readfirstlane(t >> 6);   // wave 0..3
    const int n0 = blockIdx.x * 64;

    // stage Wa into LDS now; hold Wb in registers until after phase 1
    float4 wbr[4];
    #pragma unroll
    for (int c = 0; c < 4; ++c) {
        wbr[c] = ((const float4*)wb)[t + c * 256];
        ((float4*)sW)[t + c * 256] = ((const float4*)wa)[t + c * 256];
    }

    // gather 16 nodes per wave: acc(feature=lane) = x[n][lane] + sum_adj
    const int nbase = n0 + wv * 16;
    for (int j = 0; j < 16; ++j) {
        const int n = nbase + j;
        float acc = 0.0f;
        if (n < N_NODES) {
            acc = x[(size_t)n * D + lane];
            const int e0 = rowptr[n], e1 = rowptr[n + 1];
            int e = e0;
            for (; e + 8 <= e1; e += 8) {
                int s0 = eidx[e + 0], s1 = eidx[e + 1];
                int s2 = eidx[e + 2], s3 = eidx[e + 3];
                int s4 = eidx[e + 4], s5 = eidx[e + 5];
                int s6 = eidx[e + 6], s7 = eidx[e + 7];
                float v0 = x[(size_t)s0 * D + lane];
                float v1 = x[(size_t)s1 * D + lane];
                float v2 = x[(size_t)s2 * D + lane];
                float v3 = x[(size_t)s3 * D + lane];
                float v4 = x[(size_t)s4 * D + lane];
                float v5 = x[(size_t)s5 * D + lane];
                float v6 = x[(size_t)s6 * D + lane];
                float v7 = x[(size_t)s7 * D + lane];
                acc += ((v0 + v1) + (v2 + v3)) + ((v4 + v5) + (v6 + v7));
            }
            for (; e < e1; ++e)
                acc += x[(size_t)eidx[e] * D + lane];
        }
        sX[lane * D + SWZ(lane, wv * 16 + j)] = acc;
    }
    __syncthreads();

    const int tn4 = (t & 15) * 4;   // nodes tn4..tn4+3
    const int tod = t >> 4;         // od group
    const int tod4 = tod * 4;

    float acc[4][4];
    {
        float4 bav = ((const float4*)ba)[tod];
        #pragma unroll
        for (int i = 0; i < 4; ++i) {
            acc[i][0] = bav.x; acc[i][1] = bav.y;
            acc[i][2] = bav.z; acc[i][3] = bav.w;
        }
    }
    #pragma unroll 4
    for (int k = 0; k < D; ++k) {
        const float4 xf = *(const float4*)(&sX[k * D + SWZ(k, tn4)]);
        const float4 wf = *(const float4*)(&sW[k * D + tod4]);
        const float xv[4] = {xf.x, xf.y, xf.z, xf.w};
        const float wv4[4] = {wf.x, wf.y, wf.z, wf.w};
        #pragma unroll
        for (int i = 0; i < 4; ++i)
            #pragma unroll
            for (int j = 0; j < 4; ++j)
                acc[i][j] = fmaf(xv[i], wv4[j], acc[i][j]);
    }
    __syncthreads();

    // write relu(h) (swizzled) into sX; stage Wb into sW
    #pragma unroll
    for (int j = 0; j < 4; ++j) {
        float4 hv = make_float4(fmaxf(acc[0][j], 0.f), fmaxf(acc[1][j], 0.f),
                                fmaxf(acc[2][j], 0.f), fmaxf(acc[3][j], 0.f));
        int r = tod4 + j;
        *(float4*)(&sX[r * D + SWZ(r, tn4)]) = hv;
    }
    #pragma unroll
    for (int c = 0; c < 4; ++c)
        ((float4*)sW)[t + c * 256] = wbr[c];
    __syncthreads();

    {
        float4 bbv = ((const float4*)bb)[tod];
        #pragma unroll
        for (int i = 0; i < 4; ++i) {
            acc[i][0] = bbv.x; acc[i][1] = bbv.y;
            acc[i][2] = bbv.z; acc[i][3] = bbv.w;
        }
    }
    #pragma unroll 4
    for (int k = 0; k < D; ++k) {
        const float4 xf = *(const float4*)(&sX[k * D + SWZ(k, tn4)]);
        const float4 wf = *(const float4*)(&sW[k * D + tod4]);
        const float xv[4] = {xf.x, xf.y, xf.z, xf.w};
        const float wv4[4] = {wf.x, wf.y, wf.z, wf.w};
        #pragma unroll
        for (int i = 0; i < 4; ++i)
            #pragma unroll
            for (int j = 0; j < 4; ++j)
                acc[i][j] = fmaf(xv[i], wv4[j], acc[i][j]);
    }

    #pragma unroll
    for (int i = 0; i < 4; ++i) {
        int gn = n0 + tn4 + i;
        if (gn < N_NODES) {
            float4 ov = make_float4(fmaxf(acc[i][0], 0.f), fmaxf(acc[i][1], 0.f),
                                    fmaxf(acc[i][2], 0.f), fmaxf(acc[i][3], 0.f));
            ((float4*)xout)[(size_t)gn * 16 + tod] = ov;
        }
    }
}

// ---------------- pool + final linear ----------------
__global__ __launch_bounds__(64) void pool_kernel(
    const float* __restrict__ xf, const int* __restrict__ start,
    const float* __restrict__ wl, const float* __restrict__ bl,
    float* __restrict__ out)
{
    int g = blockIdx.x, d = threadIdx.x;
    int s = start[g], e = start[g + 1];
    float sum = 0.f;
    int i = s;
    for (; i + 4 <= e; i += 4) {
        float a = xf[(size_t)(i + 0) * D + d];
        float b = xf[(size_t)(i + 1) * D + d];
        float c = xf[(size_t)(i + 2) * D + d];
        float dd = xf[(size_t)(i + 3) * D + d];
        sum += (a + b) + (c + dd);
    }
    for (; i < e; ++i) sum += xf[(size_t)i * D + d];
    float c = fmaxf((float)(e - s), 1.0f);
    float v = (sum / c) * wl[d];
    for (int off = 32; off > 0; off >>= 1)
        v += __shfl_down(v, off, 64);
    if (d == 0) out[g] = v + bl[0];
}

extern "C" void kernel_launch(void* const* d_in, const int* in_sizes, int n_in,
                              void* d_out, int out_size, void* d_ws, size_t ws_size,
                              hipStream_t stream) {
    const float* feat  = (const float*)d_in[0];
    const int*   ei    = (const int*)d_in[1];
    const int*   batch = (const int*)d_in[2];
    const float* w1a = (const float*)d_in[3];
    const float* b1a = (const float*)d_in[4];
    const float* w1b = (const float*)d_in[5];
    const float* b1b = (const float*)d_in[6];
    const float* w2a = (const float*)d_in[7];
    const float* b2a = (const float*)d_in[8];
    const float* w2b = (const float*)d_in[9];
    const float* b2b = (const float*)d_in[10];
    const float* w3a = (const float*)d_in[11];
    const float* b3a = (const float*)d_in[12];
    const float* w3b = (const float*)d_in[13];
    const float* b3b = (const float*)d_in[14];
    const float* wl  = (const float*)d_in[15];
    const float* bl  = (const float*)d_in[16];
    const int* src = ei;
    const int* dst = ei + N_EDGES;

    char* w = (char*)d_ws;
    float* buf0   = (float*)w;  w += (size_t)N_NODES * D * sizeof(float);
    float* buf1   = (float*)w;  w += (size_t)N_NODES * D * sizeof(float);
    int*   rowptr = (int*)w;    w += (size_t)(N_NODES + 1) * sizeof(int);
    int*   deg    = (int*)w;    w += (size_t)N_NODES * sizeof(int);
    int*   rank   = (int*)w;    w += (size_t)N_EDGES * sizeof(int);
    int*   eidx   = (int*)w;    w += (size_t)N_EDGES * sizeof(int);
    int*   start  = (int*)w;    w += (size_t)(N_GRAPHS + 1) * sizeof(int);
    float* out    = (float*)d_out;

    const int scanBlocks = (N_NODES + 255) / 256;   // 196
    const int edgeGrid   = (N_EDGES + 255) / 256;   // 3125
    const int layerGrid  = (N_NODES + 63) / 64;     // 782

    // CSR build: prep, one atomic pass, single-block scan, non-atomic scatter.
    prep_kernel<<<scanBlocks, 256, 0, stream>>>(batch, deg, start);
    hist_rank_kernel<<<edgeGrid, 256, 0, stream>>>(dst, deg, rank);
    scan_all_kernel<<<1, SCAN_T, 0, stream>>>(deg, rowptr);
    fill_scatter_kernel<<<edgeGrid, 256, 0, stream>>>(src, dst, rank, rowptr, eidx);

    // 3 fused GIN layers (gather + MLP in one kernel)
    gin_fused_kernel<<<layerGrid, 256, 0, stream>>>(feat, rowptr, eidx,
        w1a, b1a, w1b, b1b, buf0);
    gin_fused_kernel<<<layerGrid, 256, 0, stream>>>(buf0, rowptr, eidx,
        w2a, b2a, w2b, b2b, buf1);
    gin_fused_kernel<<<layerGrid, 256, 0, stream>>>(buf1, rowptr, eidx,
        w3a, b3a, w3b, b3b, buf0);

    pool_kernel<<<N_GRAPHS, dim3(64), 0, stream>>>(buf0, start, wl, bl, out);
}

// Round 8
// 212.394 us; speedup vs baseline: 1.5334x; 1.5334x over previous
//
#include <hip/hip_runtime.h>

#define N_NODES 50000
#define N_EDGES 800000
#define N_GRAPHS 512
#define D 64

typedef unsigned short bfu;

__device__ __forceinline__ float bf2f(bfu u) {
    return __uint_as_float(((unsigned)u) << 16);
}
__device__ __forceinline__ bfu f2bf(float f) {
    unsigned x = __float_as_uint(f);
    unsigned r = (x + 0x7fffu + ((x >> 16) & 1u)) >> 16;   // RNE
    return (bfu)r;
}

// ---------------- prep: zero deg + graph start offsets ----------------
__global__ __launch_bounds__(256) void prep_kernel(
    const int* __restrict__ batch, int* __restrict__ deg, int* __restrict__ start)
{
    int i = blockIdx.x * 256 + threadIdx.x;
    if (i < N_NODES / 4)
        ((int4*)deg)[i] = make_int4(0, 0, 0, 0);
    if (i < N_NODES) {
        int g = batch[i];
        int gp = (i == 0) ? -1 : batch[i - 1];
        for (int gg = gp + 1; gg <= g; ++gg) start[gg] = i;
        if (i == N_NODES - 1)
            for (int gg = g + 1; gg <= N_GRAPHS; ++gg) start[gg] = N_NODES;
    }
}

// ---------------- feat f32 -> bf16 ----------------
__global__ __launch_bounds__(256) void convert_kernel(
    const float* __restrict__ x, bfu* __restrict__ xb)
{
    int i = blockIdx.x * 256 + threadIdx.x;   // one float4 -> one ushort4
    float4 v = ((const float4*)x)[i];
    ushort4 o;
    o.x = f2bf(v.x); o.y = f2bf(v.y); o.z = f2bf(v.z); o.w = f2bf(v.w);
    ((ushort4*)xb)[i] = o;
}

// ---------------- CSR build (by dst), ONE atomic pass ----------------
__global__ __launch_bounds__(256) void hist_rank_kernel(
    const int* __restrict__ dst, int* __restrict__ deg, int* __restrict__ rank)
{
    int e = blockIdx.x * blockDim.x + threadIdx.x;
    if (e < N_EDGES) rank[e] = atomicAdd(&deg[dst[e]], 1);
}

__global__ __launch_bounds__(256) void scan1_kernel(
    const int* __restrict__ deg, int* __restrict__ excl,
    int* __restrict__ bsum, int n)
{
    __shared__ int s[256];
    int t = threadIdx.x;
    int i = blockIdx.x * 256 + t;
    int v = (i < n) ? deg[i] : 0;
    s[t] = v;
    __syncthreads();
    for (int off = 1; off < 256; off <<= 1) {
        int x = (t >= off) ? s[t - off] : 0;
        __syncthreads();
        s[t] += x;
        __syncthreads();
    }
    if (i < n) excl[i] = s[t] - v;
    if (t == 255) bsum[blockIdx.x] = s[255];
}

__global__ __launch_bounds__(256) void scan2_kernel(
    const int* __restrict__ bsum, int* __restrict__ boffs, int nblocks)
{
    __shared__ int s[256];
    int t = threadIdx.x;
    int v = (t < nblocks) ? bsum[t] : 0;
    s[t] = v;
    __syncthreads();
    for (int off = 1; off < 256; off <<= 1) {
        int x = (t >= off) ? s[t - off] : 0;
        __syncthreads();
        s[t] += x;
        __syncthreads();
    }
    if (t < nblocks) boffs[t] = s[t] - v;
}

__global__ __launch_bounds__(256) void scan3_kernel(
    int* __restrict__ rowptr, const int* __restrict__ boffs, int n)
{
    int i = blockIdx.x * 256 + threadIdx.x;
    if (i < n) rowptr[i] += boffs[blockIdx.x];
    if (blockIdx.x == 0 && threadIdx.x == 0) rowptr[n] = N_EDGES;
}

__global__ __launch_bounds__(256) void fill_scatter_kernel(
    const int* __restrict__ src, const int* __restrict__ dst,
    const int* __restrict__ rank, const int* __restrict__ rowptr,
    int* __restrict__ eidx)
{
    int e = blockIdx.x * blockDim.x + threadIdx.x;
    if (e < N_EDGES) eidx[rowptr[dst[e]] + rank[e]] = src[e];
}

// ---------------- gather (bf16 in, f32 out): one WAVE per node ----------------
// wid uniform -> rowptr/eidx via scalar cache; x row = 128B coalesced wave
// load (ushort/lane); f32 accumulate. Unroll 8 keeps 8 row-loads in flight.
__global__ __launch_bounds__(256) void gather_kernel(
    const bfu* __restrict__ xb, const int* __restrict__ rowptr,
    const int* __restrict__ eidx, float* __restrict__ agg)
{
    const int wid = __builtin_amdgcn_readfirstlane(
        (int)((blockIdx.x * 256 + threadIdx.x) >> 6));
    const int lane = threadIdx.x & 63;

    float acc = bf2f(xb[(size_t)wid * D + lane]);
    const int e0 = rowptr[wid], e1 = rowptr[wid + 1];
    int e = e0;
    for (; e + 8 <= e1; e += 8) {
        int s0 = eidx[e + 0], s1 = eidx[e + 1];
        int s2 = eidx[e + 2], s3 = eidx[e + 3];
        int s4 = eidx[e + 4], s5 = eidx[e + 5];
        int s6 = eidx[e + 6], s7 = eidx[e + 7];
        float v0 = bf2f(xb[(size_t)s0 * D + lane]);
        float v1 = bf2f(xb[(size_t)s1 * D + lane]);
        float v2 = bf2f(xb[(size_t)s2 * D + lane]);
        float v3 = bf2f(xb[(size_t)s3 * D + lane]);
        float v4 = bf2f(xb[(size_t)s4 * D + lane]);
        float v5 = bf2f(xb[(size_t)s5 * D + lane]);
        float v6 = bf2f(xb[(size_t)s6 * D + lane]);
        float v7 = bf2f(xb[(size_t)s7 * D + lane]);
        acc += ((v0 + v1) + (v2 + v3)) + ((v4 + v5) + (v6 + v7));
    }
    for (; e < e1; ++e)
        acc += bf2f(xb[(size_t)eidx[e] * D + lane]);
    agg[(size_t)wid * D + lane] = acc;
}

// ---------------- MLP: y = relu(relu(agg@wa+ba)@wb+bb) ----------------
// OUT_BF16=1: write bf16 (feeds next gather); 0: write f32 (feeds pool).
template <int OUT_BF16>
__global__ __launch_bounds__(256) void mlp_kernel(
    const float* __restrict__ agg,
    const float* __restrict__ wa, const float* __restrict__ ba,
    const float* __restrict__ wb, const float* __restrict__ bb,
    void* __restrict__ xout)
{
    __shared__ float sX[D][D];   // [k][n], then [hk][n]
    __shared__ float sW[D][D];   // [k][od]: Wa, then Wb
    const int t = threadIdx.x;
    const int n0 = blockIdx.x * 64;

    float4 wbr[4];
    #pragma unroll
    for (int c = 0; c < 4; ++c) {
        wbr[c] = ((const float4*)wb)[t + c * 256];
        ((float4*)sW)[t + c * 256] = ((const float4*)wa)[t + c * 256];
    }

    {
        int n = t & 63;
        int kq = t >> 6;
        int gn = n0 + n;
        #pragma unroll
        for (int c = 0; c < 4; ++c) {
            float4 v = make_float4(0.f, 0.f, 0.f, 0.f);
            if (gn < N_NODES)
                v = ((const float4*)agg)[(size_t)gn * 16 + kq * 4 + c];
            int k = kq * 16 + c * 4;
            sX[k + 0][n] = v.x;
            sX[k + 1][n] = v.y;
            sX[k + 2][n] = v.z;
            sX[k + 3][n] = v.w;
        }
    }
    __syncthreads();

    const int tn4 = (t & 15) * 4;
    const int tod = t >> 4;
    const int tod4 = tod * 4;

    float acc[4][4];
    {
        float4 bav = ((const float4*)ba)[tod];
        #pragma unroll
        for (int i = 0; i < 4; ++i) {
            acc[i][0] = bav.x; acc[i][1] = bav.y;
            acc[i][2] = bav.z; acc[i][3] = bav.w;
        }
    }
    #pragma unroll 4
    for (int k = 0; k < D; ++k) {
        const float4 xf = *(const float4*)(&sX[k][tn4]);
        const float4 wf = *(const float4*)(&sW[k][tod4]);
        const float xv[4] = {xf.x, xf.y, xf.z, xf.w};
        const float wv[4] = {wf.x, wf.y, wf.z, wf.w};
        #pragma unroll
        for (int i = 0; i < 4; ++i)
            #pragma unroll
            for (int j = 0; j < 4; ++j)
                acc[i][j] = fmaf(xv[i], wv[j], acc[i][j]);
    }
    __syncthreads();

    #pragma unroll
    for (int j = 0; j < 4; ++j) {
        float4 hv = make_float4(fmaxf(acc[0][j], 0.f), fmaxf(acc[1][j], 0.f),
                                fmaxf(acc[2][j], 0.f), fmaxf(acc[3][j], 0.f));
        *(float4*)(&sX[tod4 + j][tn4]) = hv;
    }
    #pragma unroll
    for (int c = 0; c < 4; ++c)
        ((float4*)sW)[t + c * 256] = wbr[c];
    __syncthreads();

    {
        float4 bbv = ((const float4*)bb)[tod];
        #pragma unroll
        for (int i = 0; i < 4; ++i) {
            acc[i][0] = bbv.x; acc[i][1] = bbv.y;
            acc[i][2] = bbv.z; acc[i][3] = bbv.w;
        }
    }
    #pragma unroll 4
    for (int k = 0; k < D; ++k) {
        const float4 xf = *(const float4*)(&sX[k][tn4]);
        const float4 wf = *(const float4*)(&sW[k][tod4]);
        const float xv[4] = {xf.x, xf.y, xf.z, xf.w};
        const float wv[4] = {wf.x, wf.y, wf.z, wf.w};
        #pragma unroll
        for (int i = 0; i < 4; ++i)
            #pragma unroll
            for (int j = 0; j < 4; ++j)
                acc[i][j] = fmaf(xv[i], wv[j], acc[i][j]);
    }

    #pragma unroll
    for (int i = 0; i < 4; ++i) {
        int gn = n0 + tn4 + i;
        if (gn < N_NODES) {
            float o0 = fmaxf(acc[i][0], 0.f), o1 = fmaxf(acc[i][1], 0.f);
            float o2 = fmaxf(acc[i][2], 0.f), o3 = fmaxf(acc[i][3], 0.f);
            if (OUT_BF16) {
                ushort4 ov;
                ov.x = f2bf(o0); ov.y = f2bf(o1); ov.z = f2bf(o2); ov.w = f2bf(o3);
                ((ushort4*)xout)[(size_t)gn * 16 + tod] = ov;
            } else {
                ((float4*)xout)[(size_t)gn * 16 + tod] =
                    make_float4(o0, o1, o2, o3);
            }
        }
    }
}

// ---------------- pool + final linear ----------------
__global__ __launch_bounds__(64) void pool_kernel(
    const float* __restrict__ xf, const int* __restrict__ start,
    const float* __restrict__ wl, const float* __restrict__ bl,
    float* __restrict__ out)
{
    int g = blockIdx.x, d = threadIdx.x;
    int s = start[g], e = start[g + 1];
    float sum = 0.f;
    int i = s;
    for (; i + 4 <= e; i += 4) {
        float a = xf[(size_t)(i + 0) * D + d];
        float b = xf[(size_t)(i + 1) * D + d];
        float c = xf[(size_t)(i + 2) * D + d];
        float dd = xf[(size_t)(i + 3) * D + d];
        sum += (a + b) + (c + dd);
    }
    for (; i < e; ++i) sum += xf[(size_t)i * D + d];
    float c = fmaxf((float)(e - s), 1.0f);
    float v = (sum / c) * wl[d];
    for (int off = 32; off > 0; off >>= 1)
        v += __shfl_down(v, off, 64);
    if (d == 0) out[g] = v + bl[0];
}

extern "C" void kernel_launch(void* const* d_in, const int* in_sizes, int n_in,
                              void* d_out, int out_size, void* d_ws, size_t ws_size,
                              hipStream_t stream) {
    const float* feat  = (const float*)d_in[0];
    const int*   ei    = (const int*)d_in[1];
    const int*   batch = (const int*)d_in[2];
    const float* w1a = (const float*)d_in[3];
    const float* b1a = (const float*)d_in[4];
    const float* w1b = (const float*)d_in[5];
    const float* b1b = (const float*)d_in[6];
    const float* w2a = (const float*)d_in[7];
    const float* b2a = (const float*)d_in[8];
    const float* w2b = (const float*)d_in[9];
    const float* b2b = (const float*)d_in[10];
    const float* w3a = (const float*)d_in[11];
    const float* b3a = (const float*)d_in[12];
    const float* w3b = (const float*)d_in[13];
    const float* b3b = (const float*)d_in[14];
    const float* wl  = (const float*)d_in[15];
    const float* bl  = (const float*)d_in[16];
    const int* src = ei;
    const int* dst = ei + N_EDGES;

    char* w = (char*)d_ws;
    float* agg    = (float*)w;  w += (size_t)N_NODES * D * sizeof(float);
    float* buf0   = (float*)w;  w += (size_t)N_NODES * D * sizeof(float);
    bfu*   xb     = (bfu*)w;    w += (size_t)N_NODES * D * sizeof(bfu);
    int*   rowptr = (int*)w;    w += (size_t)(N_NODES + 1) * sizeof(int);
    int*   deg    = (int*)w;    w += (size_t)N_NODES * sizeof(int);
    int*   rank   = (int*)w;    w += (size_t)N_EDGES * sizeof(int);
    int*   eidx   = (int*)w;    w += (size_t)N_EDGES * sizeof(int);
    int*   bsum   = (int*)w;    w += 256 * sizeof(int);
    int*   boffs  = (int*)w;    w += 256 * sizeof(int);
    int*   start  = (int*)w;    w += (size_t)(N_GRAPHS + 1) * sizeof(int);
    float* out    = (float*)d_out;

    const int scanBlocks = (N_NODES + 255) / 256;         // 196
    const int edgeGrid   = (N_EDGES + 255) / 256;         // 3125
    const int gatherGrid = N_NODES * 64 / 256;            // 12500 (1 wave/node)
    const int mlpGrid    = (N_NODES + 63) / 64;           // 782
    const int convGrid   = N_NODES * D / 4 / 256;         // 3125 exact

    // CSR build: prep (zero deg + gstart), one atomic pass, 3-kernel scan,
    // non-atomic scatter. (Single-block scan was 93us -- one CU, reverted.)
    prep_kernel<<<scanBlocks, 256, 0, stream>>>(batch, deg, start);
    hist_rank_kernel<<<edgeGrid, 256, 0, stream>>>(dst, deg, rank);
    scan1_kernel<<<scanBlocks, 256, 0, stream>>>(deg, rowptr, bsum, N_NODES);
    scan2_kernel<<<1, 256, 0, stream>>>(bsum, boffs, scanBlocks);
    scan3_kernel<<<scanBlocks, 256, 0, stream>>>(rowptr, boffs, N_NODES);
    fill_scatter_kernel<<<edgeGrid, 256, 0, stream>>>(src, dst, rank, rowptr, eidx);

    // feat -> bf16 (xb is reused as every layer's bf16 activation buffer:
    // each gather fully consumes xb before the layer's MLP rewrites it)
    convert_kernel<<<convGrid, 256, 0, stream>>>(feat, xb);

    // layer 1
    gather_kernel<<<gatherGrid, 256, 0, stream>>>(xb, rowptr, eidx, agg);
    mlp_kernel<1><<<mlpGrid, 256, 0, stream>>>(agg, w1a, b1a, w1b, b1b, xb);
    // layer 2
    gather_kernel<<<gatherGrid, 256, 0, stream>>>(xb, rowptr, eidx, agg);
    mlp_kernel<1><<<mlpGrid, 256, 0, stream>>>(agg, w2a, b2a, w2b, b2b, xb);
    // layer 3
    gather_kernel<<<gatherGrid, 256, 0, stream>>>(xb, rowptr, eidx, agg);
    mlp_kernel<0><<<mlpGrid, 256, 0, stream>>>(agg, w3a, b3a, w3b, b3b, buf0);

    pool_kernel<<<N_GRAPHS, dim3(64), 0, stream>>>(buf0, start, wl, bl, out);
}

// Round 9
// 194.092 us; speedup vs baseline: 1.6780x; 1.0943x over previous
//
#include <hip/hip_runtime.h>

#define N_NODES 50000
#define N_EDGES 800000
#define N_GRAPHS 512
#define D 64

typedef unsigned short bfu;

__device__ __forceinline__ float bf2f(bfu u) {
    return __uint_as_float(((unsigned)u) << 16);
}
__device__ __forceinline__ bfu f2bf(float f) {
    unsigned x = __float_as_uint(f);
    unsigned r = (x + 0x7fffu + ((x >> 16) & 1u)) >> 16;   // RNE
    return (bfu)r;
}

// ---------------- prep: zero deg + gstart + feat->bf16, one kernel ----------
// grid 3125x256 = 800000 threads: one float4->ushort4 conversion each;
// tid<12500 also zeroes deg (int4); tid<50000 also computes start[].
__global__ __launch_bounds__(256) void prep_conv_kernel(
    const float* __restrict__ feat, const int* __restrict__ batch,
    int* __restrict__ deg, int* __restrict__ start, bfu* __restrict__ xb)
{
    int i = blockIdx.x * 256 + threadIdx.x;
    float4 v = ((const float4*)feat)[i];
    ushort4 o;
    o.x = f2bf(v.x); o.y = f2bf(v.y); o.z = f2bf(v.z); o.w = f2bf(v.w);
    ((ushort4*)xb)[i] = o;
    if (i < N_NODES / 4)
        ((int4*)deg)[i] = make_int4(0, 0, 0, 0);
    if (i < N_NODES) {
        int g = batch[i];
        int gp = (i == 0) ? -1 : batch[i - 1];
        for (int gg = gp + 1; gg <= g; ++gg) start[gg] = i;
        if (i == N_NODES - 1)
            for (int gg = g + 1; gg <= N_GRAPHS; ++gg) start[gg] = N_NODES;
    }
}

// ---------------- CSR build (by dst), ONE atomic pass ----------------
__global__ __launch_bounds__(256) void hist_rank_kernel(
    const int* __restrict__ dst, int* __restrict__ deg, int* __restrict__ rank)
{
    int e = blockIdx.x * blockDim.x + threadIdx.x;
    if (e < N_EDGES) rank[e] = atomicAdd(&deg[dst[e]], 1);
}

__global__ __launch_bounds__(256) void scan1_kernel(
    const int* __restrict__ deg, int* __restrict__ excl,
    int* __restrict__ bsum, int n)
{
    __shared__ int s[256];
    int t = threadIdx.x;
    int i = blockIdx.x * 256 + t;
    int v = (i < n) ? deg[i] : 0;
    s[t] = v;
    __syncthreads();
    for (int off = 1; off < 256; off <<= 1) {
        int x = (t >= off) ? s[t - off] : 0;
        __syncthreads();
        s[t] += x;
        __syncthreads();
    }
    if (i < n) excl[i] = s[t] - v;
    if (t == 255) bsum[blockIdx.x] = s[255];
}

__global__ __launch_bounds__(256) void scan2_kernel(
    const int* __restrict__ bsum, int* __restrict__ boffs, int nblocks)
{
    __shared__ int s[256];
    int t = threadIdx.x;
    int v = (t < nblocks) ? bsum[t] : 0;
    s[t] = v;
    __syncthreads();
    for (int off = 1; off < 256; off <<= 1) {
        int x = (t >= off) ? s[t - off] : 0;
        __syncthreads();
        s[t] += x;
        __syncthreads();
    }
    if (t < nblocks) boffs[t] = s[t] - v;
}

__global__ __launch_bounds__(256) void scan3_kernel(
    int* __restrict__ rowptr, const int* __restrict__ boffs, int n)
{
    int i = blockIdx.x * 256 + threadIdx.x;
    if (i < n) rowptr[i] += boffs[blockIdx.x];
    if (blockIdx.x == 0 && threadIdx.x == 0) rowptr[n] = N_EDGES;
}

__global__ __launch_bounds__(256) void fill_scatter_kernel(
    const int* __restrict__ src, const int* __restrict__ dst,
    const int* __restrict__ rank, const int* __restrict__ rowptr,
    int* __restrict__ eidx)
{
    int e = blockIdx.x * blockDim.x + threadIdx.x;
    if (e < N_EDGES) eidx[rowptr[dst[e]] + rank[e]] = src[e];
}

// ---------------- gather: 4 nodes per WAVE (16 lanes x ushort4 per row) -----
// One VMEM instruction moves 4 different rows (512B); unroll 4 keeps 16 row
// loads in flight. f32 accumulate, float4 store.
__global__ __launch_bounds__(256) void gather_kernel(
    const bfu* __restrict__ xb, const int* __restrict__ rowptr,
    const int* __restrict__ eidx, float* __restrict__ agg)
{
    const int t = blockIdx.x * 256 + threadIdx.x;
    const int lane = threadIdx.x & 63;
    const int g = lane >> 4;        // node group 0..3 within wave
    const int q = lane & 15;        // ushort4 slice 0..15
    const int n = (t >> 6) * 4 + g; // node id (12500 waves x 4 = 50000 exact)

    const ushort4* xrow = (const ushort4*)(xb + (size_t)n * D);
    ushort4 v0 = xrow[q];
    float a0 = bf2f(v0.x), a1 = bf2f(v0.y), a2 = bf2f(v0.z), a3 = bf2f(v0.w);

    const int e1 = rowptr[n + 1];
    int e = rowptr[n];
    for (; e + 4 <= e1; e += 4) {
        int s0 = eidx[e + 0], s1 = eidx[e + 1];
        int s2 = eidx[e + 2], s3 = eidx[e + 3];
        ushort4 r0 = ((const ushort4*)(xb + (size_t)s0 * D))[q];
        ushort4 r1 = ((const ushort4*)(xb + (size_t)s1 * D))[q];
        ushort4 r2 = ((const ushort4*)(xb + (size_t)s2 * D))[q];
        ushort4 r3 = ((const ushort4*)(xb + (size_t)s3 * D))[q];
        a0 += (bf2f(r0.x) + bf2f(r1.x)) + (bf2f(r2.x) + bf2f(r3.x));
        a1 += (bf2f(r0.y) + bf2f(r1.y)) + (bf2f(r2.y) + bf2f(r3.y));
        a2 += (bf2f(r0.z) + bf2f(r1.z)) + (bf2f(r2.z) + bf2f(r3.z));
        a3 += (bf2f(r0.w) + bf2f(r1.w)) + (bf2f(r2.w) + bf2f(r3.w));
    }
    for (; e < e1; ++e) {
        ushort4 r = ((const ushort4*)(xb + (size_t)eidx[e] * D))[q];
        a0 += bf2f(r.x); a1 += bf2f(r.y); a2 += bf2f(r.z); a3 += bf2f(r.w);
    }
    ((float4*)agg)[(size_t)n * 16 + q] = make_float4(a0, a1, a2, a3);
}

// ---------------- MLP: y = relu(relu(agg@wa+ba)@wb+bb) ----------------
// OUT_BF16=1: write bf16 (feeds next gather); 0: write f32 (feeds pool).
template <int OUT_BF16>
__global__ __launch_bounds__(256) void mlp_kernel(
    const float* __restrict__ agg,
    const float* __restrict__ wa, const float* __restrict__ ba,
    const float* __restrict__ wb, const float* __restrict__ bb,
    void* __restrict__ xout)
{
    __shared__ float sX[D][D];   // [k][n], then [hk][n]
    __shared__ float sW[D][D];   // [k][od]: Wa, then Wb
    const int t = threadIdx.x;
    const int n0 = blockIdx.x * 64;

    float4 wbr[4];
    #pragma unroll
    for (int c = 0; c < 4; ++c) {
        wbr[c] = ((const float4*)wb)[t + c * 256];
        ((float4*)sW)[t + c * 256] = ((const float4*)wa)[t + c * 256];
    }

    {
        int n = t & 63;
        int kq = t >> 6;
        int gn = n0 + n;
        #pragma unroll
        for (int c = 0; c < 4; ++c) {
            float4 v = make_float4(0.f, 0.f, 0.f, 0.f);
            if (gn < N_NODES)
                v = ((const float4*)agg)[(size_t)gn * 16 + kq * 4 + c];
            int k = kq * 16 + c * 4;
            sX[k + 0][n] = v.x;
            sX[k + 1][n] = v.y;
            sX[k + 2][n] = v.z;
            sX[k + 3][n] = v.w;
        }
    }
    __syncthreads();

    const int tn4 = (t & 15) * 4;
    const int tod = t >> 4;
    const int tod4 = tod * 4;

    float acc[4][4];
    {
        float4 bav = ((const float4*)ba)[tod];
        #pragma unroll
        for (int i = 0; i < 4; ++i) {
            acc[i][0] = bav.x; acc[i][1] = bav.y;
            acc[i][2] = bav.z; acc[i][3] = bav.w;
        }
    }
    #pragma unroll 4
    for (int k = 0; k < D; ++k) {
        const float4 xf = *(const float4*)(&sX[k][tn4]);
        const float4 wf = *(const float4*)(&sW[k][tod4]);
        const float xv[4] = {xf.x, xf.y, xf.z, xf.w};
        const float wv[4] = {wf.x, wf.y, wf.z, wf.w};
        #pragma unroll
        for (int i = 0; i < 4; ++i)
            #pragma unroll
            for (int j = 0; j < 4; ++j)
                acc[i][j] = fmaf(xv[i], wv[j], acc[i][j]);
    }
    __syncthreads();

    #pragma unroll
    for (int j = 0; j < 4; ++j) {
        float4 hv = make_float4(fmaxf(acc[0][j], 0.f), fmaxf(acc[1][j], 0.f),
                                fmaxf(acc[2][j], 0.f), fmaxf(acc[3][j], 0.f));
        *(float4*)(&sX[tod4 + j][tn4]) = hv;
    }
    #pragma unroll
    for (int c = 0; c < 4; ++c)
        ((float4*)sW)[t + c * 256] = wbr[c];
    __syncthreads();

    {
        float4 bbv = ((const float4*)bb)[tod];
        #pragma unroll
        for (int i = 0; i < 4; ++i) {
            acc[i][0] = bbv.x; acc[i][1] = bbv.y;
            acc[i][2] = bbv.z; acc[i][3] = bbv.w;
        }
    }
    #pragma unroll 4
    for (int k = 0; k < D; ++k) {
        const float4 xf = *(const float4*)(&sX[k][tn4]);
        const float4 wf = *(const float4*)(&sW[k][tod4]);
        const float xv[4] = {xf.x, xf.y, xf.z, xf.w};
        const float wv[4] = {wf.x, wf.y, wf.z, wf.w};
        #pragma unroll
        for (int i = 0; i < 4; ++i)
            #pragma unroll
            for (int j = 0; j < 4; ++j)
                acc[i][j] = fmaf(xv[i], wv[j], acc[i][j]);
    }

    #pragma unroll
    for (int i = 0; i < 4; ++i) {
        int gn = n0 + tn4 + i;
        if (gn < N_NODES) {
            float o0 = fmaxf(acc[i][0], 0.f), o1 = fmaxf(acc[i][1], 0.f);
            float o2 = fmaxf(acc[i][2], 0.f), o3 = fmaxf(acc[i][3], 0.f);
            if (OUT_BF16) {
                ushort4 ov;
                ov.x = f2bf(o0); ov.y = f2bf(o1); ov.z = f2bf(o2); ov.w = f2bf(o3);
                ((ushort4*)xout)[(size_t)gn * 16 + tod] = ov;
            } else {
                ((float4*)xout)[(size_t)gn * 16 + tod] =
                    make_float4(o0, o1, o2, o3);
            }
        }
    }
}

// ---------------- pool + final linear ----------------
__global__ __launch_bounds__(64) void pool_kernel(
    const float* __restrict__ xf, const int* __restrict__ start,
    const float* __restrict__ wl, const float* __restrict__ bl,
    float* __restrict__ out)
{
    int g = blockIdx.x, d = threadIdx.x;
    int s = start[g], e = start[g + 1];
    float sum = 0.f;
    int i = s;
    for (; i + 4 <= e; i += 4) {
        float a = xf[(size_t)(i + 0) * D + d];
        float b = xf[(size_t)(i + 1) * D + d];
        float c = xf[(size_t)(i + 2) * D + d];
        float dd = xf[(size_t)(i + 3) * D + d];
        sum += (a + b) + (c + dd);
    }
    for (; i < e; ++i) sum += xf[(size_t)i * D + d];
    float c = fmaxf((float)(e - s), 1.0f);
    float v = (sum / c) * wl[d];
    for (int off = 32; off > 0; off >>= 1)
        v += __shfl_down(v, off, 64);
    if (d == 0) out[g] = v + bl[0];
}

extern "C" void kernel_launch(void* const* d_in, const int* in_sizes, int n_in,
                              void* d_out, int out_size, void* d_ws, size_t ws_size,
                              hipStream_t stream) {
    const float* feat  = (const float*)d_in[0];
    const int*   ei    = (const int*)d_in[1];
    const int*   batch = (const int*)d_in[2];
    const float* w1a = (const float*)d_in[3];
    const float* b1a = (const float*)d_in[4];
    const float* w1b = (const float*)d_in[5];
    const float* b1b = (const float*)d_in[6];
    const float* w2a = (const float*)d_in[7];
    const float* b2a = (const float*)d_in[8];
    const float* w2b = (const float*)d_in[9];
    const float* b2b = (const float*)d_in[10];
    const float* w3a = (const float*)d_in[11];
    const float* b3a = (const float*)d_in[12];
    const float* w3b = (const float*)d_in[13];
    const float* b3b = (const float*)d_in[14];
    const float* wl  = (const float*)d_in[15];
    const float* bl  = (const float*)d_in[16];
    const int* src = ei;
    const int* dst = ei + N_EDGES;

    char* w = (char*)d_ws;
    float* agg    = (float*)w;  w += (size_t)N_NODES * D * sizeof(float);
    float* buf0   = (float*)w;  w += (size_t)N_NODES * D * sizeof(float);
    bfu*   xb     = (bfu*)w;    w += (size_t)N_NODES * D * sizeof(bfu);
    int*   rowptr = (int*)w;    w += (size_t)(N_NODES + 1) * sizeof(int);
    int*   deg    = (int*)w;    w += (size_t)N_NODES * sizeof(int);
    int*   rank   = (int*)w;    w += (size_t)N_EDGES * sizeof(int);
    int*   eidx   = (int*)w;    w += (size_t)N_EDGES * sizeof(int);
    int*   bsum   = (int*)w;    w += 256 * sizeof(int);
    int*   boffs  = (int*)w;    w += 256 * sizeof(int);
    int*   start  = (int*)w;    w += (size_t)(N_GRAPHS + 1) * sizeof(int);
    float* out    = (float*)d_out;

    const int scanBlocks = (N_NODES + 255) / 256;         // 196
    const int edgeGrid   = (N_EDGES + 255) / 256;         // 3125
    const int gatherGrid = N_NODES / 16;                  // 3125 (4 nodes/wave)
    const int mlpGrid    = (N_NODES + 63) / 64;           // 782

    // prep (zero deg + gstart + feat->bf16), one atomic pass, 3-kernel scan,
    // non-atomic scatter.
    prep_conv_kernel<<<edgeGrid, 256, 0, stream>>>(feat, batch, deg, start, xb);
    hist_rank_kernel<<<edgeGrid, 256, 0, stream>>>(dst, deg, rank);
    scan1_kernel<<<scanBlocks, 256, 0, stream>>>(deg, rowptr, bsum, N_NODES);
    scan2_kernel<<<1, 256, 0, stream>>>(bsum, boffs, scanBlocks);
    scan3_kernel<<<scanBlocks, 256, 0, stream>>>(rowptr, boffs, N_NODES);
    fill_scatter_kernel<<<edgeGrid, 256, 0, stream>>>(src, dst, rank, rowptr, eidx);

    // layer 1
    gather_kernel<<<gatherGrid, 256, 0, stream>>>(xb, rowptr, eidx, agg);
    mlp_kernel<1><<<mlpGrid, 256, 0, stream>>>(agg, w1a, b1a, w1b, b1b, xb);
    // layer 2
    gather_kernel<<<gatherGrid, 256, 0, stream>>>(xb, rowptr, eidx, agg);
    mlp_kernel<1><<<mlpGrid, 256, 0, stream>>>(agg, w2a, b2a, w2b, b2b, xb);
    // layer 3
    gather_kernel<<<gatherGrid, 256, 0, stream>>>(xb, rowptr, eidx, agg);
    mlp_kernel<0><<<mlpGrid, 256, 0, stream>>>(agg, w3a, b3a, w3b, b3b, buf0);

    pool_kernel<<<N_GRAPHS, dim3(64), 0, stream>>>(buf0, start, wl, bl, out);
}